// Round 10
// baseline (182.796 us; speedup 1.0000x reference)
//
#include <hip/hip_runtime.h>
#include <math.h>

#define DHID   784
#define HID    1024
#define NB     10
#define MC_LD  800                         // padded leading dim for Mc rows
#define M2_OFF (11*MC_LD)                  // 8800
#define M2_LD  20                          // 16B-aligned rows; 2-way banks only
#define C0_OFF (M2_OFF + 64*M2_LD)         // 10080
#define WS_FLOATS 10096                    // 2524 float4
#define DELTA0 7.0f

typedef float v2f __attribute__((ext_vector_type(2)));
typedef float v4f __attribute__((ext_vector_type(4)));

// DPP rotate-add: 16-lane allreduce on the VALU pipe (no LDS traffic).
template <int CTRL>
__device__ __forceinline__ float dpp_add(float v) {
  int t = __builtin_amdgcn_update_dpp(0, __float_as_int(v), CTRL, 0xF, 0xF, false);
  return v + __int_as_float(t);
}
__device__ __forceinline__ float red16(float v) {
  v = dpp_add<0x121>(v);   // row_ror:1
  v = dpp_add<0x122>(v);   // row_ror:2
  v = dpp_add<0x124>(v);   // row_ror:4
  v = dpp_add<0x128>(v);   // row_ror:8
  return v;
}

// ---------------------------------------------------------------------------
// prep: fold all weights (unchanged). ws layout (floats):
//   [0 .. 8800)    Mc[11][800]; [8800..10080) M2[64][20];
//   [10080..10090) c0[10]; [10090] bmean.
// g[j] = 2 if j<5 else 1 (spiking gains provably constant).
// ---------------------------------------------------------------------------
__global__ __launch_bounds__(256) void prep_kernel(
    const float* __restrict__ W_in,  const float* __restrict__ b_in,
    const float* __restrict__ W_ph,  const float* __restrict__ b_ph,
    const float* __restrict__ W_out, const float* __restrict__ b_out,
    float* __restrict__ ws) {
  __shared__ float wlds[HID * 11];           // 44 KB
  const int tid = threadIdx.x;

  for (int idx = tid; idx < HID * NB; idx += 256) {
    const int j = idx / NB;
    const int c = idx - j * NB;
    wlds[j * 11 + c] = W_out[idx];
  }
  __syncthreads();

  const int w = tid >> 6;
  const int l = tid & 63;
  const int b = blockIdx.x * 4 + w;          // 0..783 W_in; 784..847 W_ph; 848 bias
  if (b > DHID + 64) return;

  float acc[11];
#pragma unroll
  for (int c = 0; c < 11; ++c) acc[c] = 0.f;

#pragma unroll 4
  for (int it = 0; it < 16; ++it) {
    const int j = l + 64 * it;
    float wv, extra;
    if (b < DHID)           { wv = W_in[b * HID + j];          extra = wv;      }
    else if (b < DHID + 64) { wv = W_ph[(b - DHID) * HID + j]; extra = 0.f;     }
    else                    { wv = b_in[j] + b_ph[j];          extra = b_in[j]; }
    const float wg = (j < 5) ? 2.0f * wv : wv;
    const float* wr = &wlds[j * 11];
#pragma unroll
    for (int c = 0; c < 10; ++c) acc[c] += wg * wr[c];
    acc[10] += extra;
  }

#pragma unroll
  for (int c = 0; c < 11; ++c) {
    float v = acc[c];
    v += __shfl_xor(v, 1,  64);
    v += __shfl_xor(v, 2,  64);
    v += __shfl_xor(v, 4,  64);
    v += __shfl_xor(v, 8,  64);
    v += __shfl_xor(v, 16, 64);
    v += __shfl_xor(v, 32, 64);
    acc[c] = v;
  }

  if (l == 0) {
    if (b < DHID) {
#pragma unroll
      for (int c = 0; c < 10; ++c) ws[c * MC_LD + b] = acc[c];
      ws[10 * MC_LD + b] = acc[10] * (1.0f / HID);
    } else if (b < DHID + 64) {
      const int h = b - DHID;
#pragma unroll
      for (int c = 0; c < 10; ++c) ws[M2_OFF + h * M2_LD + c] = acc[c];
    } else {
#pragma unroll
      for (int c = 0; c < 10; ++c) ws[C0_OFF + c] = acc[c] + b_out[c];
      ws[C0_OFF + 10] = acc[10] * (1.0f / HID);
    }
  }
}

// ---------------------------------------------------------------------------
// mainx4: main_G with an in-kernel repeat loop (reps=4). Writes the SAME
// output every rep (deterministic). Purpose: single ~60us dispatch that
// outranks the 39us harness fills in the rocprof top-5 -> main's counters.
// Opaque zoff per rep prevents cross-rep CSE of the x loads.
// ---------------------------------------------------------------------------
__global__ __launch_bounds__(256, 2) void mainx4_kernel(
    const float* __restrict__ x, const float* __restrict__ ws,
    float* __restrict__ out, int reps) {
  __shared__ __align__(16) float lds[WS_FLOATS];
  const int tid = threadIdx.x;

  for (int idx = tid; idx < WS_FLOATS / 4; idx += 256)
    ((v4f*)lds)[idx] = ((const v4f*)ws)[idx];
  __syncthreads();

  const int wav  = tid >> 6;
  const int lane = tid & 63;
  const int kl   = lane & 15;
  const int rsub = lane >> 4;
  const int row  = blockIdx.x * 32 + wav * 8 + rsub * 2;
  const float* x0 = x + (size_t)row * DHID;
  const int d0 = 4 * kl;

  // M2 hoist once (LDS, not under test)
  float mA[10], mB[10], mC[10], mD[10];
  {
    const float* p;
    p = &lds[M2_OFF + (kl)      * M2_LD];
    *(v4f*)&mA[0] = *(const v4f*)p;  *(v4f*)&mA[4] = *(const v4f*)(p + 4);
    *(v2f*)&mA[8] = *(const v2f*)(p + 8);
    p = &lds[M2_OFF + (kl + 16) * M2_LD];
    *(v4f*)&mB[0] = *(const v4f*)p;  *(v4f*)&mB[4] = *(const v4f*)(p + 4);
    *(v2f*)&mB[8] = *(const v2f*)(p + 8);
    p = &lds[M2_OFF + (kl + 32) * M2_LD];
    *(v4f*)&mC[0] = *(const v4f*)p;  *(v4f*)&mC[4] = *(const v4f*)(p + 4);
    *(v2f*)&mC[8] = *(const v2f*)(p + 8);
    p = &lds[M2_OFF + (kl + 48) * M2_LD];
    *(v4f*)&mD[0] = *(const v4f*)p;  *(v4f*)&mD[4] = *(const v4f*)(p + 4);
    *(v2f*)&mD[8] = *(const v2f*)(p + 8);
  }
  const float bmean = lds[C0_OFF + 10];
  const float c0v   = lds[C0_OFF + (kl < 10 ? kl : 0)];

#pragma unroll 1
  for (int rep = 0; rep < reps; ++rep) {
    int zoff = 0;
    asm volatile("" : "+v"(zoff));          // opaque 0: forces re-load per rep
    const float* xr = x0 + zoff;

    v2f acc0[11], acc1[11];
#pragma unroll
    for (int c = 0; c < 11; ++c) { acc0[c] = (v2f)0.f; acc1[c] = (v2f)0.f; }

    v4f sa[4], sb[4];
#pragma unroll
    for (int i = 0; i < 3; ++i) {
      sa[i] = *(const v4f*)(xr + d0 + 64 * i);
      sb[i] = *(const v4f*)(xr + DHID + d0 + 64 * i);
    }
    v4f ta = (v4f)0.f, tb = (v4f)0.f;
    if (kl < 4) {
      ta = *(const v4f*)(xr + 768 + 4 * kl);
      tb = *(const v4f*)(xr + DHID + 768 + 4 * kl);
    }

#pragma unroll
    for (int i = 0; i < 12; ++i) {
      if (i + 3 < 12) {
        const int dn = d0 + 64 * (i + 3);
        sa[(i + 3) & 3] = *(const v4f*)(xr + dn);
        sb[(i + 3) & 3] = *(const v4f*)(xr + DHID + dn);
      }
      const v4f xa = sa[i & 3];
      const v4f xb = sb[i & 3];
      const int d = d0 + 64 * i;
#pragma unroll
      for (int c = 0; c < 11; ++c) {
        const v4f mv = *(const v4f*)(&lds[c * MC_LD + d]);
        acc0[c] += xa.lo * mv.lo;  acc0[c] += xa.hi * mv.hi;
        acc1[c] += xb.lo * mv.lo;  acc1[c] += xb.hi * mv.hi;
      }
    }
    if (kl < 4) {
      const int d = 768 + 4 * kl;
#pragma unroll
      for (int c = 0; c < 11; ++c) {
        const v4f mv = *(const v4f*)(&lds[c * MC_LD + d]);
        acc0[c] += ta.lo * mv.lo;  acc0[c] += ta.hi * mv.hi;
        acc1[c] += tb.lo * mv.lo;  acc1[c] += tb.hi * mv.hi;
      }
    }

    float s0[11], s1[11];
#pragma unroll
    for (int c = 0; c < 11; ++c) {
      s0[c] = red16(acc0[c].x + acc0[c].y);
      s1[c] = red16(acc1[c].x + acc1[c].y);
    }

    const float base0 = DELTA0 * (s0[10] + bmean);
    const float base1 = DELTA0 * (s1[10] + bmean);
    float sA0, cA0, sB0, cB0, sA1, cA1, sB1, cB1;
    __sincosf((float)(kl + 1)  * base0, &sA0, &cA0);
    __sincosf((float)(kl + 17) * base0, &sB0, &cB0);
    __sincosf((float)(kl + 1)  * base1, &sA1, &cA1);
    __sincosf((float)(kl + 17) * base1, &sB1, &cB1);

    float t0[10], t1[10];
#pragma unroll
    for (int c = 0; c < 10; ++c) {
      t0[c] = red16(cA0 * mA[c] + cB0 * mB[c] + sA0 * mC[c] + sB0 * mD[c]);
      t1[c] = red16(cA1 * mA[c] + cB1 * mB[c] + sA1 * mC[c] + sB1 * mD[c]);
    }

    float o0 = 0.f, o1 = 0.f;
#pragma unroll
    for (int c = 0; c < 10; ++c) {
      o0 = (kl == c) ? s0[c] + t0[c] : o0;
      o1 = (kl == c) ? s1[c] + t1[c] : o1;
    }
    if (kl < 10) {
      out[(size_t)row * NB + kl]       = o0 + c0v;
      out[(size_t)(row + 1) * NB + kl] = o1 + c0v;
    }
  }
}

// ---------------------------------------------------------------------------
// stream probes: ideal pattern (wave reads 1KB contiguous per instruction),
// grid-stride over x, `passes` full passes. Writes nothing (asm keepalive).
// Two names so the two grid configs are distinguishable in the counter table.
// ---------------------------------------------------------------------------
__device__ __forceinline__ void stream_body(const float* __restrict__ x,
                                            int passes) {
  const size_t n4     = (size_t)16384 * DHID / 4;    // 3,211,264 float4
  const size_t stride = (size_t)gridDim.x * 256;
  float s = 0.f;
#pragma unroll 1
  for (int p = 0; p < passes; ++p) {
    int zoff = 0;
    asm volatile("" : "+v"(zoff));
    v4f vs = (v4f)0.f;
    for (size_t j = (size_t)blockIdx.x * 256 + threadIdx.x + zoff; j < n4;
         j += stride)
      vs += ((const v4f*)x)[j];
    s += vs.x + vs.y + vs.z + vs.w;
  }
  asm volatile("" :: "v"(s));
}
__global__ __launch_bounds__(256) void stream_g512(const float* __restrict__ x,
                                                   int passes) {
  stream_body(x, passes);
}
__global__ __launch_bounds__(256) void stream_g2048(const float* __restrict__ x,
                                                    int passes) {
  stream_body(x, passes);
}

// ---------------------------------------------------------------------------
extern "C" void kernel_launch(void* const* d_in, const int* in_sizes, int n_in,
                              void* d_out, int out_size, void* d_ws, size_t ws_size,
                              hipStream_t stream) {
  const float* x     = (const float*)d_in[0];
  const float* W_in  = (const float*)d_in[1];
  const float* b_in  = (const float*)d_in[2];
  const float* W_ph  = (const float*)d_in[3];
  const float* b_ph  = (const float*)d_in[4];
  const float* W_out = (const float*)d_in[5];
  const float* b_out = (const float*)d_in[6];
  float* out = (float*)d_out;
  float* ws  = (float*)d_ws;

  // dur10 = 5.78 + prep(3.3) + mainx4 + stream512x8 + stream2048x7
  // All three long dispatches exceed the 39us fills -> their counters surface.
  prep_kernel<<<(DHID + 64 + 1 + 3) / 4, 256, 0, stream>>>(W_in, b_in, W_ph, b_ph,
                                                           W_out, b_out, ws);
  mainx4_kernel<<<512, 256, 0, stream>>>(x, ws, out, 4);
  stream_g512<<<512, 256, 0, stream>>>(x, 8);
  stream_g2048<<<2048, 256, 0, stream>>>(x, 7);
}

// Round 11
// 63.070 us; speedup vs baseline: 2.8983x; 2.8983x over previous
//
#include <hip/hip_runtime.h>
#include <math.h>

#define DHID   784
#define HID    1024
#define NB     10
#define MC_LD  788                          // 788*4B = 3152B, 16B-aligned rows
#define M2_OFF (11*MC_LD)                   // 8668
#define M2_LD  13                           // stride-13 scalar reads: conflict-free
#define C0_OFF (M2_OFF + 64*M2_LD)          // 9500 ; c0[10] + bmean at +10
#define WS_PAD 9512                         // staged floats (mult of 4)
#define RED_OFF 9512                        // per-wave reduce scratch (4x176)
#define LDS_FLOATS (RED_OFF + 4*176)        // 10216 floats = 40864B -> 40KB alloc
#define DELTA0 7.0f

typedef float v2f __attribute__((ext_vector_type(2)));
typedef float v4f __attribute__((ext_vector_type(4)));

template <int CTRL>
__device__ __forceinline__ float dpp_add(float v) {
  int t = __builtin_amdgcn_update_dpp(0, __float_as_int(v), CTRL, 0xF, 0xF, false);
  return v + __int_as_float(t);
}
__device__ __forceinline__ float red16(float v) {
  v = dpp_add<0x121>(v);   // row_ror:1
  v = dpp_add<0x122>(v);   // row_ror:2
  v = dpp_add<0x124>(v);   // row_ror:4
  v = dpp_add<0x128>(v);   // row_ror:8
  return v;                // all 16 lanes of the row hold the row total
}

// ---------------------------------------------------------------------------
// prep: fold all weights. ws layout (floats):
//   [0 .. 8668)   Mc[11][788]: c<10 -> col c of M1 = W_in @ (g .* W_out)
//                              c==10 -> w_mean[d] = (1/1024)*sum_j W_in[d][j]
//   [8668..9500)  M2[64][13]: M2[h][c] = sum_j W_ph[h][j]*g[j]*W_out[j][c]
//   [9500..9510)  c0[10] = (b_in+b_ph)*g @ W_out + b_out ;  [9510] bmean
// g[j] = 2 if j<5 else 1 (spiking gains provably constant: each top-k token
// spikes once and resets to 0 -> V all-zero -> top_k -> indices 0..4).
// ---------------------------------------------------------------------------
__global__ __launch_bounds__(256) void prep_kernel(
    const float* __restrict__ W_in,  const float* __restrict__ b_in,
    const float* __restrict__ W_ph,  const float* __restrict__ b_ph,
    const float* __restrict__ W_out, const float* __restrict__ b_out,
    float* __restrict__ ws) {
  __shared__ float wlds[HID * 11];           // 44 KB
  const int tid = threadIdx.x;

  for (int idx = tid; idx < HID * NB; idx += 256) {
    const int j = idx / NB;
    const int c = idx - j * NB;
    wlds[j * 11 + c] = W_out[idx];
  }
  __syncthreads();

  const int w = tid >> 6;
  const int l = tid & 63;
  const int b = blockIdx.x * 4 + w;          // 0..783 W_in; 784..847 W_ph; 848 bias
  if (b > DHID + 64) return;

  float acc[11];
#pragma unroll
  for (int c = 0; c < 11; ++c) acc[c] = 0.f;

#pragma unroll 4
  for (int it = 0; it < 16; ++it) {
    const int j = l + 64 * it;
    float wv, extra;
    if (b < DHID)           { wv = W_in[b * HID + j];          extra = wv;      }
    else if (b < DHID + 64) { wv = W_ph[(b - DHID) * HID + j]; extra = 0.f;     }
    else                    { wv = b_in[j] + b_ph[j];          extra = b_in[j]; }
    const float wg = (j < 5) ? 2.0f * wv : wv;
    const float* wr = &wlds[j * 11];
#pragma unroll
    for (int c = 0; c < 10; ++c) acc[c] += wg * wr[c];
    acc[10] += extra;
  }

#pragma unroll
  for (int c = 0; c < 11; ++c) {
    float v = acc[c];
    v += __shfl_xor(v, 1,  64);
    v += __shfl_xor(v, 2,  64);
    v += __shfl_xor(v, 4,  64);
    v += __shfl_xor(v, 8,  64);
    v += __shfl_xor(v, 16, 64);
    v += __shfl_xor(v, 32, 64);
    acc[c] = v;
  }

  if (l == 0) {
    if (b < DHID) {
#pragma unroll
      for (int c = 0; c < 10; ++c) ws[c * MC_LD + b] = acc[c];
      ws[10 * MC_LD + b] = acc[10] * (1.0f / HID);
    } else if (b < DHID + 64) {
      const int h = b - DHID;
#pragma unroll
      for (int c = 0; c < 10; ++c) ws[M2_OFF + h * M2_LD + c] = acc[c];
    } else {
#pragma unroll
      for (int c = 0; c < 10; ++c) ws[C0_OFF + c] = acc[c] + b_out[c];
      ws[C0_OFF + 10] = acc[10] * (1.0f / HID);
    }
  }
}

// ---------------------------------------------------------------------------
// main_H: wave-contiguous x loads. Wave = 4 rows; chunk i = 256 consecutive
// floats of one row -> every global load = 1KB contiguous. 1024 blocks,
// 4 blocks/CU (40KB LDS), 16 waves/CU. Reduce: DPP red16 + 8 LDS scratch ops.
// ---------------------------------------------------------------------------
__global__ __launch_bounds__(256, 2) void main_kernel_H(
    const float* __restrict__ x, const float* __restrict__ ws,
    float* __restrict__ out) {
  __shared__ __align__(16) float lds[LDS_FLOATS];
  const int tid  = threadIdx.x;
  const int wav  = tid >> 6;
  const int lane = tid & 63;
  const int row0 = blockIdx.x * 16 + wav * 4;
  const float* x0 = x + (size_t)row0 * DHID + 4 * lane;

  // issue chunk-0 loads first: HBM stream starts while we stage weights
  v4f xa0, xa1, xa2, xa3;
  xa0 = *(const v4f*)(x0);
  xa1 = *(const v4f*)(x0 + DHID);
  xa2 = *(const v4f*)(x0 + 2 * DHID);
  xa3 = *(const v4f*)(x0 + 3 * DHID);

  for (int idx = tid; idx < WS_PAD / 4; idx += 256)
    ((v4f*)lds)[idx] = ((const v4f*)ws)[idx];
  __syncthreads();

  float acc[4][11];
#pragma unroll
  for (int r = 0; r < 4; ++r)
#pragma unroll
    for (int c = 0; c < 11; ++c) acc[r][c] = 0.f;

  // chunk 1 issue
  v4f xb0 = *(const v4f*)(x0 + 256);
  v4f xb1 = *(const v4f*)(x0 + DHID + 256);
  v4f xb2 = *(const v4f*)(x0 + 2 * DHID + 256);
  v4f xb3 = *(const v4f*)(x0 + 3 * DHID + 256);

  // consume chunk 0 (d = 4*lane)
#pragma unroll
  for (int c = 0; c < 11; ++c) {
    const v4f mv = *(const v4f*)(&lds[c * MC_LD + 4 * lane]);
    acc[0][c] += xa0.x * mv.x + xa0.y * mv.y + xa0.z * mv.z + xa0.w * mv.w;
    acc[1][c] += xa1.x * mv.x + xa1.y * mv.y + xa1.z * mv.z + xa1.w * mv.w;
    acc[2][c] += xa2.x * mv.x + xa2.y * mv.y + xa2.z * mv.z + xa2.w * mv.w;
    acc[3][c] += xa3.x * mv.x + xa3.y * mv.y + xa3.z * mv.z + xa3.w * mv.w;
  }

  // chunk 2 issue
  xa0 = *(const v4f*)(x0 + 512);
  xa1 = *(const v4f*)(x0 + DHID + 512);
  xa2 = *(const v4f*)(x0 + 2 * DHID + 512);
  xa3 = *(const v4f*)(x0 + 3 * DHID + 512);

  // consume chunk 1 (d = 256 + 4*lane)
#pragma unroll
  for (int c = 0; c < 11; ++c) {
    const v4f mv = *(const v4f*)(&lds[c * MC_LD + 256 + 4 * lane]);
    acc[0][c] += xb0.x * mv.x + xb0.y * mv.y + xb0.z * mv.z + xb0.w * mv.w;
    acc[1][c] += xb1.x * mv.x + xb1.y * mv.y + xb1.z * mv.z + xb1.w * mv.w;
    acc[2][c] += xb2.x * mv.x + xb2.y * mv.y + xb2.z * mv.z + xb2.w * mv.w;
    acc[3][c] += xb3.x * mv.x + xb3.y * mv.y + xb3.z * mv.z + xb3.w * mv.w;
  }

  // merged tail issue: ONE conditional load covers all 4 rows' last 16 floats
  v4f xt = (v4f)0.f;
  if (lane < 16)
    xt = *(const v4f*)(x + (size_t)(row0 + (lane >> 2)) * DHID + 768 + 4 * (lane & 3));

  // consume chunk 2 (d = 512 + 4*lane)
#pragma unroll
  for (int c = 0; c < 11; ++c) {
    const v4f mv = *(const v4f*)(&lds[c * MC_LD + 512 + 4 * lane]);
    acc[0][c] += xa0.x * mv.x + xa0.y * mv.y + xa0.z * mv.z + xa0.w * mv.w;
    acc[1][c] += xa1.x * mv.x + xa1.y * mv.y + xa1.z * mv.z + xa1.w * mv.w;
    acc[2][c] += xa2.x * mv.x + xa2.y * mv.y + xa2.z * mv.z + xa2.w * mv.w;
    acc[3][c] += xa3.x * mv.x + xa3.y * mv.y + xa3.z * mv.z + xa3.w * mv.w;
  }

  // consume tail: per-row masked copies (xt is 0 on lanes >= 16)
  {
    const int tr = (lane >> 2) & 3;
    v4f xs0 = (tr == 0) ? xt : (v4f)0.f;
    v4f xs1 = (tr == 1) ? xt : (v4f)0.f;
    v4f xs2 = (tr == 2) ? xt : (v4f)0.f;
    v4f xs3 = (tr == 3) ? xt : (v4f)0.f;
#pragma unroll
    for (int c = 0; c < 11; ++c) {
      const v4f mv = *(const v4f*)(&lds[c * MC_LD + 768 + 4 * (lane & 3)]);
      acc[0][c] += xs0.x * mv.x + xs0.y * mv.y + xs0.z * mv.z + xs0.w * mv.w;
      acc[1][c] += xs1.x * mv.x + xs1.y * mv.y + xs1.z * mv.z + xs1.w * mv.w;
      acc[2][c] += xs2.x * mv.x + xs2.y * mv.y + xs2.z * mv.z + xs2.w * mv.w;
      acc[3][c] += xs3.x * mv.x + xs3.y * mv.y + xs3.z * mv.z + xs3.w * mv.w;
    }
  }

  // stage 1: DPP 16-lane reduce (VALU pipe)
#pragma unroll
  for (int r = 0; r < 4; ++r)
#pragma unroll
    for (int c = 0; c < 11; ++c) acc[r][c] = red16(acc[r][c]);

  // stage 2: cross-group combine via per-wave LDS scratch (8 LDS ops)
  const int g   = lane >> 4;
  const int c16 = lane & 15;
  float* red = &lds[RED_OFF + wav * 176];
  float mine[4];
#pragma unroll
  for (int r = 0; r < 4; ++r) {
    float v = 0.f;
#pragma unroll
    for (int c = 0; c < 11; ++c) v = (c16 == c) ? acc[r][c] : v;
    mine[r] = v;
  }
  if (c16 < 11) {
#pragma unroll
    for (int r = 0; r < 4; ++r) red[(g * 4 + r) * 11 + c16] = mine[r];
  }
  __syncthreads();
  float sv = 0.f;                      // s_g[c16]: group g owns row g
  if (c16 < 11) {
#pragma unroll
    for (int gp = 0; gp < 4; ++gp) sv += red[(gp * 4 + g) * 11 + c16];
  }

  // phasor tail for row g: lane c16 owns harmonics c16+1 and c16+17
  const float bmean = lds[C0_OFF + 10];
  const float s10  = __shfl(sv, (lane & 48) + 10, 64);
  const float base = DELTA0 * (s10 + bmean);
  float sA, cA, sB, cB;
  __sincosf((float)(c16 + 1)  * base, &sA, &cA);
  __sincosf((float)(c16 + 17) * base, &sB, &cB);

  float t[10];
#pragma unroll
  for (int c = 0; c < 10; ++c) {
    const float v = cA * lds[M2_OFF + (c16)      * M2_LD + c]
                  + cB * lds[M2_OFF + (c16 + 16) * M2_LD + c]
                  + sA * lds[M2_OFF + (c16 + 32) * M2_LD + c]
                  + sB * lds[M2_OFF + (c16 + 48) * M2_LD + c];
    t[c] = red16(v);
  }

  float tv = 0.f;
#pragma unroll
  for (int c = 0; c < 10; ++c) tv = (c16 == c) ? t[c] : tv;
  if (c16 < 10)
    out[(size_t)(row0 + g) * NB + c16] = sv + tv + lds[C0_OFF + c16];
}

// ---------------------------------------------------------------------------
extern "C" void kernel_launch(void* const* d_in, const int* in_sizes, int n_in,
                              void* d_out, int out_size, void* d_ws, size_t ws_size,
                              hipStream_t stream) {
  const float* x     = (const float*)d_in[0];
  const float* W_in  = (const float*)d_in[1];
  const float* b_in  = (const float*)d_in[2];
  const float* W_ph  = (const float*)d_in[3];
  const float* b_ph  = (const float*)d_in[4];
  const float* W_out = (const float*)d_in[5];
  const float* b_out = (const float*)d_in[6];
  float* out = (float*)d_out;
  float* ws  = (float*)d_ws;

  // dur11 = ovh(5.78) + prep + 3*main_H
  prep_kernel<<<(DHID + 64 + 1 + 3) / 4, 256, 0, stream>>>(W_in, b_in, W_ph, b_ph,
                                                           W_out, b_out, ws);
  main_kernel_H<<<1024, 256, 0, stream>>>(x, ws, out);
  main_kernel_H<<<1024, 256, 0, stream>>>(x, ws, out);
  main_kernel_H<<<1024, 256, 0, stream>>>(x, ws, out);
}